// Round 1
// baseline (1147.087 us; speedup 1.0000x reference)
//
#include <hip/hip_runtime.h>

// Problem constants (match reference)
#define BATCH 256
#define IMH 1024
#define IMW 1024
#define KSZ 33
#define KHALF 16
#define PATCH 34      // KSZ + 1 (bilinear needs +1 row/col)
#define PSTRIDE 35    // +1 pad to break LDS bank alias patterns

__global__ __launch_bounds__(256)
void lkpe_kernel(const float* __restrict__ m,
                 const float* __restrict__ coords,
                 const float* __restrict__ kern,
                 float* __restrict__ out)
{
    __shared__ float sP[PATCH * PSTRIDE];   // 34x34 patch, padded stride
    __shared__ float sK[KSZ * KSZ];         // 33x33 kernel
    __shared__ float sPart[4];              // per-wave partials

    const int b = blockIdx.x;
    const int t = threadIdx.x;

    // Per-block scalars: fractional coords -> integer base + bilinear weights.
    // dx,dy are integers, so frac(xs) == frac(cx) for EVERY tap; the padded
    // border clamp never binds for coords in [0, W-1). (See analysis.)
    const float cx = coords[2 * b + 0];
    const float cy = coords[2 * b + 1];
    const float fxf = floorf(cx);
    const float fyf = floorf(cy);
    const float wx = cx - fxf;
    const float wy = cy - fyf;
    const int Fx = (int)fxf;
    const int Fy = (int)fyf;

    const float* __restrict__ mb = m + (size_t)b * (IMH * IMW);

    // Stage the 34x34 wrapped patch. (Fy-16+r) can reach -16; since IMH is a
    // power of two, two's-complement AND with (IMH-1) is the true mod.
    for (int e = t; e < PATCH * PATCH; e += 256) {
        int r = e / PATCH;
        int c = e - r * PATCH;
        int row = (Fy - KHALF + r) & (IMH - 1);
        int col = (Fx - KHALF + c) & (IMW - 1);
        sP[r * PSTRIDE + c] = mb[row * IMW + col];
    }
    // Stage the kernel (shared across blocks; comes from L2 after block 0).
    for (int e = t; e < KSZ * KSZ; e += 256) sK[e] = kern[e];
    __syncthreads();

    const float w00 = (1.0f - wx) * (1.0f - wy);
    const float w01 = wx * (1.0f - wy);
    const float w10 = (1.0f - wx) * wy;
    const float w11 = wx * wy;

    // Each thread covers taps t, t+256, ... (<= 5 each).
    float s = 0.0f;
    for (int e = t; e < KSZ * KSZ; e += 256) {
        int i = e / KSZ;
        int j = e - i * KSZ;
        const float* p = &sP[i * PSTRIDE + j];
        float v = w00 * p[0] + w01 * p[1]
                + w10 * p[PSTRIDE] + w11 * p[PSTRIDE + 1];
        s = fmaf(sK[e], v, s);
    }

    // Wave(64)-wide shuffle reduction, then combine the 4 wave partials.
    #pragma unroll
    for (int off = 32; off > 0; off >>= 1) s += __shfl_down(s, off);
    if ((t & 63) == 0) sPart[t >> 6] = s;
    __syncthreads();
    if (t == 0) out[b] = sPart[0] + sPart[1] + sPart[2] + sPart[3];
}

extern "C" void kernel_launch(void* const* d_in, const int* in_sizes, int n_in,
                              void* d_out, int out_size, void* d_ws, size_t ws_size,
                              hipStream_t stream) {
    const float* m      = (const float*)d_in[0];   // [256,1,1024,1024] fp32
    const float* coords = (const float*)d_in[1];   // [256,2] fp32 (x,y)
    const float* kern   = (const float*)d_in[2];   // [33,33] fp32
    float* out          = (float*)d_out;           // [256,1] fp32

    lkpe_kernel<<<BATCH, 256, 0, stream>>>(m, coords, kern, out);
}

// Round 2
// 1113.900 us; speedup vs baseline: 1.0298x; 1.0298x over previous
//
#include <hip/hip_runtime.h>

// Problem constants (match reference)
#define BATCH 256
#define IMH 1024
#define IMW 1024
#define KSZ 33
#define KHALF 16
#define PATCH 34      // KSZ + 1 (bilinear needs +1 row/col)
#define PSTRIDE 35    // +1 pad to break LDS bank alias patterns
#define NPATCH (PATCH * PATCH)   // 1156
#define NTAP   (KSZ * KSZ)       // 1089
#define NITER  5                 // ceil(1156/256)

__global__ __launch_bounds__(256)
void lkpe_kernel(const float* __restrict__ m,
                 const float* __restrict__ coords,
                 const float* __restrict__ kern,
                 float* __restrict__ out)
{
    __shared__ float sP[PATCH * PSTRIDE];   // 34x34 patch, padded stride
    __shared__ float sPart[4];              // per-wave partials

    const int b = blockIdx.x;
    const int t = threadIdx.x;

    // Per-block scalars: fractional coords -> integer base + bilinear weights.
    // dx,dy are integers, so frac(xs) == frac(cx) for EVERY tap; the padded
    // border clamp never binds for coords in [0, W-1).
    const float cx = coords[2 * b + 0];
    const float cy = coords[2 * b + 1];
    const float fxf = floorf(cx);
    const float fyf = floorf(cy);
    const float wx = cx - fxf;
    const float wy = cy - fyf;
    const int Fx = (int)fxf;
    const int Fy = (int)fyf;

    const float* __restrict__ mb = m + (size_t)b * (IMH * IMW);

    // --- Register-batched staging: issue ALL cold loads back-to-back so a
    // lane pays the ~900-cycle HBM latency once, not 5x serialized. Kernel
    // taps are private to a thread, so kern[] never touches LDS. ---
    float pv[NITER];   // patch values
    float kv[NITER];   // kernel-tap values
    #pragma unroll
    for (int k = 0; k < NITER; ++k) {
        int e  = t + k * 256;
        int ec = e < NPATCH ? e : (NPATCH - 1);   // clamp: always in-bounds
        int r  = ec / PATCH;
        int c  = ec - r * PATCH;
        // (Fy-16+r) can reach -16; IMH/IMW are pow2 so & gives true mod.
        int row = (Fy - KHALF + r) & (IMH - 1);
        int col = (Fx - KHALF + c) & (IMW - 1);
        pv[k] = mb[row * IMW + col];
        int et = e < NTAP ? e : (NTAP - 1);
        kv[k] = kern[et];
    }
    #pragma unroll
    for (int k = 0; k < NITER; ++k) {
        int e = t + k * 256;
        if (e < NPATCH) {
            int r = e / PATCH;
            int c = e - r * PATCH;
            sP[r * PSTRIDE + c] = pv[k];
        }
    }
    __syncthreads();

    const float w00 = (1.0f - wx) * (1.0f - wy);
    const float w01 = wx * (1.0f - wy);
    const float w10 = (1.0f - wx) * wy;
    const float w11 = wx * wy;

    // Each thread covers taps t, t+256, ... (<= 5 each).
    float s = 0.0f;
    #pragma unroll
    for (int k = 0; k < NITER; ++k) {
        int e = t + k * 256;
        if (e < NTAP) {
            int i = e / KSZ;
            int j = e - i * KSZ;
            const float* p = &sP[i * PSTRIDE + j];
            float v = w00 * p[0] + w01 * p[1]
                    + w10 * p[PSTRIDE] + w11 * p[PSTRIDE + 1];
            s = fmaf(kv[k], v, s);
        }
    }

    // Wave(64)-wide shuffle reduction, then combine the 4 wave partials.
    #pragma unroll
    for (int off = 32; off > 0; off >>= 1) s += __shfl_down(s, off);
    if ((t & 63) == 0) sPart[t >> 6] = s;
    __syncthreads();
    if (t == 0) out[b] = sPart[0] + sPart[1] + sPart[2] + sPart[3];
}

extern "C" void kernel_launch(void* const* d_in, const int* in_sizes, int n_in,
                              void* d_out, int out_size, void* d_ws, size_t ws_size,
                              hipStream_t stream) {
    const float* m      = (const float*)d_in[0];   // [256,1,1024,1024] fp32
    const float* coords = (const float*)d_in[1];   // [256,2] fp32 (x,y)
    const float* kern   = (const float*)d_in[2];   // [33,33] fp32
    float* out          = (float*)d_out;           // [256,1] fp32

    lkpe_kernel<<<BATCH, 256, 0, stream>>>(m, coords, kern, out);
}